// Round 1
// baseline (60.624 us; speedup 1.0000x reference)
//
#include <hip/hip_runtime.h>
#include <math.h>

#define NB 8
#define NQ 32
#define NK 32
#define QN 8
#define DIM 256

struct c32 { float x, y; };
__device__ __forceinline__ c32 cmul(c32 a, c32 b) {
    return { a.x*b.x - a.y*b.y, a.x*b.y + a.y*b.x };
}

// ---------------------------------------------------------------------------
// Kernel 1: v_circuit full statevector sim. One block per (b,k) state (256),
// 128 threads, state (256 complex amps) in LDS.
// ---------------------------------------------------------------------------
__global__ __launch_bounds__(128) void v_kernel(const float* __restrict__ value,
                                                const float* __restrict__ v_param,
                                                float2* __restrict__ vs) {
    __shared__ float2 st[256];
    const int s = blockIdx.x;      // b*NK + k
    const int t = threadIdx.x;     // 0..127

    // Initial layer: RY(value_i) on wire i applied to |0..0> => real product state.
    float cv[8], sv[8];
    #pragma unroll
    for (int i = 0; i < 8; ++i) {
        float v = value[s*8 + i] * 0.5f;
        cv[i] = cosf(v); sv[i] = sinf(v);
    }
    #pragma unroll
    for (int r = 0; r < 2; ++r) {
        int x = t + r*128;
        float amp = 1.f;
        #pragma unroll
        for (int i = 0; i < 8; ++i)
            amp *= ((x >> (7 - i)) & 1) ? sv[i] : cv[i];
        st[x] = make_float2(amp, 0.f);
    }
    __syncthreads();

    for (int rep = 0; rep < 6; ++rep) {
        // --- 8 single-qubit gates U = RZ(c) RY(b) RZ(a), same for all states ---
        for (int w = 0; w < 8; ++w) {
            float a  = v_param[(rep*3 + 0)*8 + w];
            float bb = v_param[(rep*3 + 1)*8 + w];
            float c  = v_param[(rep*3 + 2)*8 + w];
            float cb = cosf(bb*0.5f), sb = sinf(bb*0.5f);
            float apc = (a + c)*0.5f, amc = (a - c)*0.5f;
            float capc = cosf(apc), sapc = sinf(apc);
            float camc = cosf(amc), samc = sinf(amc);
            c32 U00 = {  cb*capc, -cb*sapc };
            c32 U01 = { -sb*camc, -sb*samc };
            c32 U10 = {  sb*camc, -sb*samc };
            c32 U11 = {  cb*capc,  cb*sapc };

            int mask = 1 << (7 - w);
            int x0 = ((t & ~(mask-1)) << 1) | (t & (mask-1));
            int x1 = x0 | mask;
            c32 s0 = { st[x0].x, st[x0].y };
            c32 s1 = { st[x1].x, st[x1].y };
            c32 n0 = { U00.x*s0.x - U00.y*s0.y + U01.x*s1.x - U01.y*s1.y,
                       U00.x*s0.y + U00.y*s0.x + U01.x*s1.y + U01.y*s1.x };
            c32 n1 = { U10.x*s0.x - U10.y*s0.y + U11.x*s1.x - U11.y*s1.y,
                       U10.x*s0.y + U10.y*s0.x + U11.x*s1.y + U11.y*s1.x };
            st[x0] = make_float2(n0.x, n0.y);
            st[x1] = make_float2(n1.x, n1.y);
            __syncthreads();
        }
        // --- composed permutation of the 8 CNOTs: control i, target (i+1+rep)%8 ---
        // s_final(x) = s(sigma_0(sigma_1(...sigma_7(x))))
        float2 tmp0, tmp1;
        #pragma unroll
        for (int r = 0; r < 2; ++r) {
            int x = t + r*128;
            int y = x;
            #pragma unroll
            for (int i = 7; i >= 0; --i) {
                int tgt = (i + 1 + rep) & 7;
                y ^= ((y >> (7 - i)) & 1) << (7 - tgt);
            }
            float2 v = st[y];
            if (r == 0) tmp0 = v; else tmp1 = v;
        }
        __syncthreads();
        st[t]       = tmp0;
        st[t + 128] = tmp1;
        __syncthreads();
    }

    // write out
    vs[s*DIM + t]       = st[t];
    vs[s*DIM + t + 128] = st[t + 128];
}

// ---------------------------------------------------------------------------
// Kernel 2: analytic attn amplitudes + suffix cumprod + weighted sum of
// v_states + sign-expectation output. One block per (b,q), 256 threads.
// ---------------------------------------------------------------------------
__global__ __launch_bounds__(256) void attn_kernel(const float* __restrict__ query,
                                                   const float* __restrict__ key,
                                                   const float* __restrict__ qk_param,
                                                   const float* __restrict__ attn_param,
                                                   const float2* __restrict__ vs,
                                                   float* __restrict__ out) {
    const int bq = blockIdx.x;
    const int b = bq >> 5;
    const int q = bq & 31;
    const int t = threadIdx.x;

    __shared__ float2 a0s[32], a1s[32];
    __shared__ float2 coeff[32];
    __shared__ float2 total_s;
    __shared__ float prob[256];
    __shared__ float red[9];

    if (t < 32) {
        const int k = t;
        c32 P = { 1.f, 0.f };
        #pragma unroll
        for (int i = 0; i < 8; ++i) {
            float qi = query[(b*NQ + q)*8 + i];
            float ki = key[(b*NK + k)*8 + i];
            float phi = attn_param[0*8 + i] + ((i > 0) ? attn_param[1*8 + (i-1)] : 0.f);
            float Th = phi + qk_param[1*8 + i] - ki;     // full angle
            float gam = qk_param[0*8 + i] * 0.5f;
            c32 f = {  cosf(gam) * cosf((Th + qi)*0.5f),
                      -sinf(gam) * cosf((Th - qi)*0.5f) };
            P = cmul(P, f);
        }
        float h = attn_param[1*8 + 7] * 0.5f;
        float s7 = sinf(h), c7 = cosf(h);
        a0s[k] = make_float2(-s7*P.x, -s7*P.y);
        a1s[k] = make_float2( c7*P.x,  c7*P.y);
    }
    __syncthreads();

    if (t == 0) {
        // suffix[k] = prod_{l>k} a0[l]; coeff[k] = suffix[k]*a1[k]; total = prod all
        c32 sfx = { 1.f, 0.f };
        for (int k = 31; k >= 0; --k) {
            c32 a1 = { a1s[k].x, a1s[k].y };
            c32 cf = cmul(sfx, a1);
            coeff[k] = make_float2(cf.x, cf.y);
            c32 a0 = { a0s[k].x, a0s[k].y };
            sfx = cmul(sfx, a0);
        }
        total_s = make_float2(sfx.x, sfx.y);
    }
    __syncthreads();

    // v_new[d] = sum_k coeff[k] * vs[b,k,d]  (+ total at d=0)
    const int d = t;
    c32 vn = { 0.f, 0.f };
    for (int k = 0; k < 32; ++k) {
        float2 cf = coeff[k];
        float2 v  = vs[(b*NK + k)*DIM + d];
        vn.x += cf.x*v.x - cf.y*v.y;
        vn.y += cf.x*v.y + cf.y*v.x;
    }
    if (d == 0) { vn.x += total_s.x; vn.y += total_s.y; }
    prob[d] = vn.x*vn.x + vn.y*vn.y;
    __syncthreads();

    if (t < 9) {
        float sum = 0.f;
        if (t == 8) {
            for (int d2 = 0; d2 < 256; ++d2) sum += prob[d2];
        } else {
            for (int d2 = 0; d2 < 256; ++d2)
                if ((d2 >> (7 - t)) & 1) sum += prob[d2];
        }
        red[t] = sum;
    }
    __syncthreads();

    if (t < 8) {
        float S = red[8];
        out[(b*NQ + q)*8 + t] = (S - 2.f*red[t]) / S;
    }
}

extern "C" void kernel_launch(void* const* d_in, const int* in_sizes, int n_in,
                              void* d_out, int out_size, void* d_ws, size_t ws_size,
                              hipStream_t stream) {
    const float* query      = (const float*)d_in[0];
    const float* key        = (const float*)d_in[1];
    const float* value      = (const float*)d_in[2];
    const float* v_param    = (const float*)d_in[3];
    const float* qk_param   = (const float*)d_in[4];
    const float* attn_param = (const float*)d_in[5];
    float2* vs = (float2*)d_ws;   // 256 states x 256 complex = 512 KB

    v_kernel<<<NB*NK, 128, 0, stream>>>(value, v_param, vs);
    attn_kernel<<<NB*NQ, 256, 0, stream>>>(query, key, qk_param, attn_param, vs,
                                           (float*)d_out);
}

// Round 2
// 25.050 us; speedup vs baseline: 2.4201x; 2.4201x over previous
//
#include <hip/hip_runtime.h>
#include <math.h>

#define NB 8
#define NQ 32
#define NK 32
#define DIM 256

struct c32 { float x, y; };
__device__ __forceinline__ c32 cmul(c32 a, c32 b) {
    return { a.x*b.x - a.y*b.y, a.x*b.y + a.y*b.x };
}

// ---------------------------------------------------------------------------
// Kernel 1: v_circuit sim, one wave (64 threads) per (b,k) state.
// Statevector lives in registers: lane = amp-index bits 7..2 (wires 0..5),
// slot r = bits 1..0 (wires 6,7). Gates on wires 0..5 -> shfl_xor;
// wires 6,7 -> register-local. CNOT layer -> LDS scatter/gather.
// All 48 gate matrices are state-independent: computed once, in parallel.
// ---------------------------------------------------------------------------
__global__ __launch_bounds__(64) void v_kernel(const float* __restrict__ value,
                                               const float* __restrict__ v_param,
                                               float2* __restrict__ vs) {
    __shared__ float2 U[48][4];    // [rep*8+w][U00,U01,U10,U11]
    __shared__ float2 pst[256];    // permutation scratch
    const int s = blockIdx.x;      // b*NK + k
    const int t = threadIdx.x;     // 0..63

    // --- parallel one-shot U-matrix build (48 lanes, 6 trig each) ---
    if (t < 48) {
        int rep = t >> 3, w = t & 7;
        float a  = v_param[(rep*3 + 0)*8 + w];
        float bb = v_param[(rep*3 + 1)*8 + w];
        float c  = v_param[(rep*3 + 2)*8 + w];
        float cb = cosf(bb*0.5f), sb = sinf(bb*0.5f);
        float apc = (a + c)*0.5f, amc = (a - c)*0.5f;
        float capc = cosf(apc), sapc = sinf(apc);
        float camc = cosf(amc), samc = sinf(amc);
        U[t][0] = make_float2( cb*capc, -cb*sapc);
        U[t][1] = make_float2(-sb*camc, -sb*samc);
        U[t][2] = make_float2( sb*camc, -sb*samc);
        U[t][3] = make_float2( cb*capc,  cb*sapc);
    }

    // --- initial RY product state (real) ---
    float cv[8], sv[8];
    #pragma unroll
    for (int i = 0; i < 8; ++i) {
        float v = value[s*8 + i] * 0.5f;
        cv[i] = cosf(v); sv[i] = sinf(v);
    }
    // wire i (0..5) <-> amp bit (7-i) <-> lane bit (5-i)
    float common = 1.f;
    #pragma unroll
    for (int i = 0; i < 6; ++i)
        common *= ((t >> (5 - i)) & 1) ? sv[i] : cv[i];
    float2 amp[4];
    amp[0] = make_float2(common*cv[6]*cv[7], 0.f);  // slot bit1=wire6, bit0=wire7
    amp[1] = make_float2(common*cv[6]*sv[7], 0.f);
    amp[2] = make_float2(common*sv[6]*cv[7], 0.f);
    amp[3] = make_float2(common*sv[6]*sv[7], 0.f);

    __syncthreads();   // U ready (single wave: cheap)

    for (int rep = 0; rep < 6; ++rep) {
        // --- gates on wires 0..5: lane-level pairing via shfl_xor ---
        #pragma unroll
        for (int w = 0; w < 6; ++w) {
            const int g = rep*8 + w;
            float2 u00 = U[g][0], u01 = U[g][1], u10 = U[g][2], u11 = U[g][3];
            const int lmask = 1 << (5 - w);
            const bool hi = (t >> (5 - w)) & 1;
            float2 u0 = hi ? u10 : u00;
            float2 u1 = hi ? u11 : u01;
            #pragma unroll
            for (int r = 0; r < 4; ++r) {
                float ox = __shfl_xor(amp[r].x, lmask);
                float oy = __shfl_xor(amp[r].y, lmask);
                float2 A = hi ? make_float2(ox, oy) : amp[r];  // amp(bit=0)
                float2 B = hi ? amp[r] : make_float2(ox, oy);  // amp(bit=1)
                amp[r].x = u0.x*A.x - u0.y*A.y + u1.x*B.x - u1.y*B.y;
                amp[r].y = u0.x*A.y + u0.y*A.x + u1.x*B.y + u1.y*B.x;
            }
        }
        // --- gates on wires 6,7: slot-local ---
        #pragma unroll
        for (int w = 6; w < 8; ++w) {
            const int g = rep*8 + w;
            float2 u00 = U[g][0], u01 = U[g][1], u10 = U[g][2], u11 = U[g][3];
            const int smask = 1 << (7 - w);   // w=6 -> 2, w=7 -> 1
            float2 na[4];
            #pragma unroll
            for (int r = 0; r < 4; ++r) {
                if ((r & smask) == 0) {
                    float2 A = amp[r], B = amp[r | smask];
                    na[r].x = u00.x*A.x - u00.y*A.y + u01.x*B.x - u01.y*B.y;
                    na[r].y = u00.x*A.y + u00.y*A.x + u01.x*B.y + u01.y*B.x;
                } else {
                    float2 A = amp[r ^ smask], B = amp[r];
                    na[r].x = u10.x*A.x - u10.y*A.y + u11.x*B.x - u11.y*B.y;
                    na[r].y = u10.x*A.y + u10.y*A.x + u11.x*B.y + u11.y*B.x;
                }
            }
            #pragma unroll
            for (int r = 0; r < 4; ++r) amp[r] = na[r];
        }
        // --- composed CNOT permutation via LDS gather ---
        #pragma unroll
        for (int r = 0; r < 4; ++r) pst[(t << 2) | r] = amp[r];
        __syncthreads();
        float2 na[4];
        #pragma unroll
        for (int r = 0; r < 4; ++r) {
            int y = (t << 2) | r;
            #pragma unroll
            for (int i = 7; i >= 0; --i) {
                int tgt = (i + 1 + rep) & 7;
                y ^= ((y >> (7 - i)) & 1) << (7 - tgt);
            }
            na[r] = pst[y];
        }
        __syncthreads();
        #pragma unroll
        for (int r = 0; r < 4; ++r) amp[r] = na[r];
    }

    // coalesced store: lane t owns contiguous amps 4t..4t+3 (32 B)
    float4* o = reinterpret_cast<float4*>(vs + s*DIM);
    o[2*t]     = make_float4(amp[0].x, amp[0].y, amp[1].x, amp[1].y);
    o[2*t + 1] = make_float4(amp[2].x, amp[2].y, amp[3].x, amp[3].y);
}

// ---------------------------------------------------------------------------
// Kernel 2: analytic attn amplitudes + suffix cumprod + weighted v_state sum
// + sign expectation. One block (256 thr) per (b,q).
// ---------------------------------------------------------------------------
__global__ __launch_bounds__(256) void attn_kernel(const float* __restrict__ query,
                                                   const float* __restrict__ key,
                                                   const float* __restrict__ qk_param,
                                                   const float* __restrict__ attn_param,
                                                   const float2* __restrict__ vs,
                                                   float* __restrict__ out) {
    const int bq = blockIdx.x;
    const int b = bq >> 5;
    const int q = bq & 31;
    const int t = threadIdx.x;

    __shared__ float2 a0s[32], a1s[32];
    __shared__ float2 coeff[32];
    __shared__ float2 total_s;
    __shared__ float prob[256];

    // --- per-(k,i) factor, 8-lane shfl product-reduce ---
    {
        const int k = t >> 3, i = t & 7;
        float qi = query[(b*NQ + q)*8 + i];
        float ki = key[(b*NK + k)*8 + i];
        float phi = attn_param[i] + ((i > 0) ? attn_param[8 + i - 1] : 0.f);
        float Th = phi + qk_param[8 + i] - ki;
        float gam = qk_param[i] * 0.5f;
        c32 f = {  cosf(gam) * cosf((Th + qi)*0.5f),
                  -sinf(gam) * cosf((Th - qi)*0.5f) };
        #pragma unroll
        for (int off = 1; off < 8; off <<= 1) {
            c32 o2 = { __shfl_xor(f.x, off), __shfl_xor(f.y, off) };
            f = cmul(f, o2);
        }
        if (i == 0) {
            float h = attn_param[15] * 0.5f;
            float s7 = sinf(h), c7 = cosf(h);
            a0s[k] = make_float2(-s7*f.x, -s7*f.y);
            a1s[k] = make_float2( c7*f.x,  c7*f.y);
        }
    }
    __syncthreads();

    if (t == 0) {   // serial suffix scan over 32 (short chain)
        c32 sfx = { 1.f, 0.f };
        for (int k = 31; k >= 0; --k) {
            c32 a1 = { a1s[k].x, a1s[k].y };
            c32 cf = cmul(sfx, a1);
            coeff[k] = make_float2(cf.x, cf.y);
            c32 a0 = { a0s[k].x, a0s[k].y };
            sfx = cmul(sfx, a0);
        }
        total_s = make_float2(sfx.x, sfx.y);
    }
    __syncthreads();

    // --- v_new[d] = sum_k coeff[k] * vs[b,k,d]  (+ total at d=0) ---
    {
        const int d = t;
        c32 vn = { 0.f, 0.f };
        #pragma unroll 8
        for (int k = 0; k < 32; ++k) {
            float2 cf = coeff[k];
            float2 v  = vs[(b*NK + k)*DIM + d];
            vn.x += cf.x*v.x - cf.y*v.y;
            vn.y += cf.x*v.y + cf.y*v.x;
        }
        if (d == 0) { vn.x += total_s.x; vn.y += total_s.y; }
        prob[d] = vn.x*vn.x + vn.y*vn.y;
    }
    __syncthreads();

    // --- 8 output wires: group g = t>>5 (32 lanes each) computes
    //     out[g] = sum_d prob*sign_g / sum_d prob via strided + shfl reduce ---
    {
        const int g = t >> 5, l = t & 31;
        float sp = 0.f, ss = 0.f;
        #pragma unroll
        for (int j = 0; j < 8; ++j) {
            int d2 = l + 32*j;
            float p = prob[d2];
            sp += p;
            ss += ((d2 >> (7 - g)) & 1) ? -p : p;
        }
        #pragma unroll
        for (int off = 1; off < 32; off <<= 1) {
            sp += __shfl_xor(sp, off);
            ss += __shfl_xor(ss, off);
        }
        if (l == 0) out[(b*NQ + q)*8 + g] = ss / sp;
    }
}

extern "C" void kernel_launch(void* const* d_in, const int* in_sizes, int n_in,
                              void* d_out, int out_size, void* d_ws, size_t ws_size,
                              hipStream_t stream) {
    const float* query      = (const float*)d_in[0];
    const float* key        = (const float*)d_in[1];
    const float* value      = (const float*)d_in[2];
    const float* v_param    = (const float*)d_in[3];
    const float* qk_param   = (const float*)d_in[4];
    const float* attn_param = (const float*)d_in[5];
    float2* vs = (float2*)d_ws;   // 256 states x 256 complex = 512 KB

    v_kernel<<<NB*NK, 64, 0, stream>>>(value, v_param, vs);
    attn_kernel<<<NB*NQ, 256, 0, stream>>>(query, key, qk_param, attn_param, vs,
                                           (float*)d_out);
}